// Round 19
// baseline (536.328 us; speedup 1.0000x reference)
//
#include <hip/hip_runtime.h>
#include <hip/hip_bf16.h>
#include <math.h>

#define LOWEST_FREQ (30.0f / 11025.0f)

typedef _Float16 f16x8 __attribute__((ext_vector_type(8)));
typedef _Float16 f16x4 __attribute__((ext_vector_type(4)));
typedef float f32x4 __attribute__((ext_vector_type(4)));

__device__ __forceinline__ float fast_sin_rev(float rev) {
#if __has_builtin(__builtin_amdgcn_sinf)
    return __builtin_amdgcn_sinf(rev);   // v_sin_f32: sin(2*pi*rev)
#else
    return __sinf(rev * 6.28318530717958647692f);
#endif
}
__device__ __forceinline__ float fast_cos_rev(float rev) {
#if __has_builtin(__builtin_amdgcn_cosf)
    return __builtin_amdgcn_cosf(rev);
#else
    return __cosf(rev * 6.28318530717958647692f);
#endif
}
__device__ __forceinline__ float lrelu(float x) { return x >= 0.f ? x : 0.2f * x; }

// ---------------- weight repack: 6 convs, OIHW fp32 -> [tap][oc][ic] fp16 hi/lo ----------------
__global__ __launch_bounds__(128) void repack_kernel(
    const float* __restrict__ w0, const float* __restrict__ w1,
    const float* __restrict__ w2, const float* __restrict__ w3,
    const float* __restrict__ w4, const float* __restrict__ w5,
    _Float16* __restrict__ whi, _Float16* __restrict__ wlo)
{
    __shared__ float s[1152];
    int bid = blockIdx.x;               // 0..767
    int j = bid >> 7, oc = bid & 127;
    const float* src = (j == 0) ? w0 : (j == 1) ? w1 : (j == 2) ? w2 :
                       (j == 3) ? w3 : (j == 4) ? w4 : w5;
    src += (size_t)oc * 1152;
    for (int i = threadIdx.x; i < 1152; i += 128) s[i] = src[i];
    __syncthreads();
    int ic = threadIdx.x;
    size_t base = (size_t)j * 147456 + (size_t)oc * 128 + ic;
    #pragma unroll
    for (int tap = 0; tap < 9; ++tap) {
        float v = s[ic * 9 + tap];
        _Float16 h = (_Float16)v;
        size_t o = base + (size_t)tap * 16384;
        whi[o] = h;
        wlo[o] = (_Float16)(v - (float)h);
    }
}

// ---------------- conv_in: 1ch -> 112ch 3x3 + concat pos; channels-last hi/lo fp16 out ----------------
__global__ __launch_bounds__(256) void conv_in_kernel(
    const float* __restrict__ x, const float* __restrict__ wi,
    const float* __restrict__ bi, const float* __restrict__ pos,
    _Float16* __restrict__ outHi, _Float16* __restrict__ outLo, int total)
{
    int idx = blockIdx.x * 256 + threadIdx.x;
    if (idx >= total) return;
    int c   = idx & 127;
    int pix = (idx >> 7) & 16383;
    int b   = idx >> 21;
    int y = pix >> 7, xx = pix & 127;
    float v;
    if (c < 112) {
        float acc = bi[c];
        const float* xb = x + (size_t)b * 16384;
        const float* wc = wi + c * 9;
        #pragma unroll
        for (int ky = 0; ky < 3; ++ky) {
            int gy = y + ky - 1;
            if ((unsigned)gy < 128u) {
                #pragma unroll
                for (int kx = 0; kx < 3; ++kx) {
                    int gx = xx + kx - 1;
                    if ((unsigned)gx < 128u)
                        acc = fmaf(wc[ky * 3 + kx], xb[gy * 128 + gx], acc);
                }
            }
        }
        v = acc;
    } else {
        v = pos[(c - 112) * 16384 + pix];
    }
    _Float16 h = (_Float16)v;
    outHi[idx] = h;
    outLo[idx] = (_Float16)(v - (float)h);
}

// ---------------- split-fp16 MFMA stride-1 3x3 conv (fp32-parity) ----------------
// PROTECTED FINAL (R4 config). Six variants tried across the session — all
// null or regressed. 2-barrier 256-thread structure at 2 blocks/CU is this
// conv's local optimum short of a full 8-phase counted-vmcnt rewrite.
template<int TH, bool UP2, bool RELU, bool SPLITOUT>
__global__ __launch_bounds__(256, 2) void mfma_conv_s1(
    const _Float16* __restrict__ inHi, const _Float16* __restrict__ inLo,
    const _Float16* __restrict__ whi, const _Float16* __restrict__ wlo,
    const float* __restrict__ bias, float* __restrict__ outF,
    _Float16* __restrict__ outHi, _Float16* __restrict__ outLo,
    int H, int W)
{
    constexpr int IR    = TH + 2;                 // input rows staged
    constexpr int ELEMS = IR * 18 * 16;           // f16x4 groups
    constexpr int NPREF = (ELEMS + 255) / 256;
    constexpr int RH    = TH / 2;                 // output rows per wave
    __shared__ __align__(16) _Float16 sAh[IR * 18 * 72];
    __shared__ __align__(16) _Float16 sAl[IR * 18 * 72];
    const int tid  = threadIdx.x;
    const int w    = tid >> 6, lane = tid & 63;
    const int wm   = w & 1, wn = w >> 1;
    const int lm   = lane & 15, lq = lane >> 4;
    const int b    = blockIdx.z >> 1;
    const int ocb  = (blockIdx.z & 1) * 64;
    const int x0   = blockIdx.x * 16, y0 = blockIdx.y * TH;
    const int iy0  = y0 - 1, ix0 = x0 - 1;
    const int Hp   = UP2 ? (H >> 1) : H;
    const int Wp   = UP2 ? (W >> 1) : W;
    const _Float16* inbH = inHi + (size_t)b * Hp * Wp * 128;
    const _Float16* inbL = inLo + (size_t)b * Hp * Wp * 128;
    const f16x4 zf4 = {(_Float16)0.f, (_Float16)0.f, (_Float16)0.f, (_Float16)0.f};

    f16x4 rh[NPREF], rl[NPREF];

#define S1_PREF(ICS)                                                          \
    _Pragma("unroll")                                                         \
    for (int i = 0; i < NPREF; ++i) {                                         \
        int e = tid + i * 256;                                                \
        rh[i] = zf4; rl[i] = zf4;                                             \
        if (e < ELEMS) {                                                      \
            int px = e >> 4, icq = e & 15;                                    \
            int row = px / 18, col = px - row * 18;                           \
            int gy = iy0 + row, gx = ix0 + col;                               \
            if ((unsigned)gy < (unsigned)H && (unsigned)gx < (unsigned)W) {   \
                int sy = UP2 ? (gy >> 1) : gy;                                \
                int sx = UP2 ? (gx >> 1) : gx;                                \
                size_t o = ((size_t)sy * Wp + sx) * 128 + (ICS) + icq * 4;    \
                rh[i] = *(const f16x4*)(inbH + o);                            \
                rl[i] = *(const f16x4*)(inbL + o);                            \
            }                                                                 \
        }                                                                     \
    }

#define S1_WRITE()                                                            \
    _Pragma("unroll")                                                         \
    for (int i = 0; i < NPREF; ++i) {                                         \
        int e = tid + i * 256;                                                \
        if (e < ELEMS) {                                                      \
            int px = e >> 4, icq = e & 15;                                    \
            *(f16x4*)&sAh[px * 72 + icq * 4] = rh[i];                         \
            *(f16x4*)&sAl[px * 72 + icq * 4] = rl[i];                         \
        }                                                                     \
    }

    f32x4 acc[RH][2];
    #pragma unroll
    for (int r = 0; r < RH; ++r)
        #pragma unroll
        for (int nt = 0; nt < 2; ++nt) acc[r][nt] = (f32x4){0.f, 0.f, 0.f, 0.f};

    S1_PREF(0)
    S1_WRITE()
    __syncthreads();

    for (int ics2 = 0; ics2 < 2; ++ics2) {
        const int ics = ics2 * 64;
        if (ics2 == 0) { S1_PREF(64) }   // global loads in flight across MFMA phase

        for (int ky = 0; ky < 3; ++ky)
        for (int kx = 0; kx < 3; ++kx) {
            const int tap = ky * 3 + kx;
            const _Float16* wth = whi + (size_t)tap * 16384;
            const _Float16* wtl = wlo + (size_t)tap * 16384;
            #pragma unroll
            for (int kc = 0; kc < 2; ++kc) {
                f16x8 bh[2], bl[2];
                #pragma unroll
                for (int nt = 0; nt < 2; ++nt) {
                    int oc = ocb + wn * 32 + nt * 16 + lm;
                    size_t o = (size_t)oc * 128 + ics + kc * 32 + lq * 8;
                    bh[nt] = *(const f16x8*)(wth + o);
                    bl[nt] = *(const f16x8*)(wtl + o);
                }
                __builtin_amdgcn_s_setprio(1);
                #pragma unroll
                for (int r = 0; r < RH; ++r) {
                    int rin = wm * RH + r + ky;
                    int cin = lm + kx;
                    int o = (rin * 18 + cin) * 72 + kc * 32 + lq * 8;
                    f16x8 ah = *(const f16x8*)(&sAh[o]);
                    f16x8 al = *(const f16x8*)(&sAl[o]);
                    #pragma unroll
                    for (int nt = 0; nt < 2; ++nt) {
                        acc[r][nt] = __builtin_amdgcn_mfma_f32_16x16x32_f16(ah, bh[nt], acc[r][nt], 0, 0, 0);
                        acc[r][nt] = __builtin_amdgcn_mfma_f32_16x16x32_f16(ah, bl[nt], acc[r][nt], 0, 0, 0);
                        acc[r][nt] = __builtin_amdgcn_mfma_f32_16x16x32_f16(al, bh[nt], acc[r][nt], 0, 0, 0);
                    }
                }
                __builtin_amdgcn_s_setprio(0);
            }
        }
        __syncthreads();                         // all reads of current chunk done
        if (ics2 == 0) { S1_WRITE() __syncthreads(); }
    }
#undef S1_PREF
#undef S1_WRITE

    float bv[2];
    #pragma unroll
    for (int nt = 0; nt < 2; ++nt) bv[nt] = bias[ocb + wn * 32 + nt * 16 + lm];
    const size_t boff = (size_t)b * H * W * 128;
    #pragma unroll
    for (int r = 0; r < RH; ++r) {
        int y = y0 + wm * RH + r;
        #pragma unroll
        for (int nt = 0; nt < 2; ++nt) {
            int oc = ocb + wn * 32 + nt * 16 + lm;
            #pragma unroll
            for (int reg = 0; reg < 4; ++reg) {
                int xo = x0 + lq * 4 + reg;
                float vv = acc[r][nt][reg] + bv[nt];
                if (RELU) vv = lrelu(vv);
                size_t oo = boff + ((size_t)y * W + xo) * 128 + oc;
                if (SPLITOUT) {
                    _Float16 hh = (_Float16)vv;
                    outHi[oo] = hh;
                    outLo[oo] = (_Float16)(vv - (float)hh);
                } else {
                    outF[oo] = vv;
                }
            }
        }
    }
}

// ---------------- split-fp16 MFMA stride-2 3x3 conv (fp32-parity) ----------------
// R7 decomposition. R19: s2#1 TH 4->2 (grid 256->512 = 2 blocks/CU; was 1).
// Halo staging +11% (5/4 vs 9/8 rows per output row) on L3-resident input.
template<int TH, bool RELU, bool SPLITOUT>
__global__ __launch_bounds__(256, 2) void mfma_conv_s2(
    const _Float16* __restrict__ inHi, const _Float16* __restrict__ inLo,
    const _Float16* __restrict__ whi, const _Float16* __restrict__ wlo,
    const float* __restrict__ bias, float* __restrict__ outF,
    _Float16* __restrict__ outHi, _Float16* __restrict__ outLo,
    int Hin, int Win)
{
    constexpr int IR    = 2 * TH + 1;            // input rows staged
    constexpr int ELEMS = IR * 33 * 8;           // f16x4 groups to stage
    constexpr int NPREF = (ELEMS + 255) / 256;
    constexpr int RH    = TH / 2;                // rows per wave
    __shared__ __align__(16) _Float16 sAh[IR * 33 * 40];
    __shared__ __align__(16) _Float16 sAl[IR * 33 * 40];
    const int tid  = threadIdx.x;
    const int w    = tid >> 6, lane = tid & 63;
    const int lm   = lane & 15, lq = lane >> 4;
    const int wm   = w & 1, wn = w >> 1;
    const int b    = blockIdx.z >> 1;
    const int ocb  = (blockIdx.z & 1) * 64;
    const int Wout = Win >> 1;
    const int x0   = blockIdx.x * 16, y0 = blockIdx.y * TH;
    const int iy0  = blockIdx.y * 2 * TH - 1, ix0 = blockIdx.x * 32 - 1;
    const _Float16* inbH = inHi + (size_t)b * Hin * Win * 128;
    const _Float16* inbL = inLo + (size_t)b * Hin * Win * 128;
    const f16x4 zf4 = {(_Float16)0.f, (_Float16)0.f, (_Float16)0.f, (_Float16)0.f};

    f16x4 rh[NPREF], rl[NPREF];

#define S2_PREF(ICS)                                                          \
    _Pragma("unroll")                                                         \
    for (int i = 0; i < NPREF; ++i) {                                         \
        int e = tid + i * 256;                                                \
        rh[i] = zf4; rl[i] = zf4;                                             \
        if (e < ELEMS) {                                                      \
            int px = e >> 3, icq = e & 7;                                     \
            int row = px / 33, col = px - row * 33;                           \
            int gy = iy0 + row, gx = ix0 + col;                               \
            if ((unsigned)gy < (unsigned)Hin && (unsigned)gx < (unsigned)Win) { \
                size_t o = ((size_t)gy * Win + gx) * 128 + (ICS) + icq * 4;   \
                rh[i] = *(const f16x4*)(inbH + o);                            \
                rl[i] = *(const f16x4*)(inbL + o);                            \
            }                                                                 \
        }                                                                     \
    }

#define S2_WRITE()                                                            \
    _Pragma("unroll")                                                         \
    for (int i = 0; i < NPREF; ++i) {                                         \
        int e = tid + i * 256;                                                \
        if (e < ELEMS) {                                                      \
            int px = e >> 3, icq = e & 7;                                     \
            *(f16x4*)&sAh[px * 40 + icq * 4] = rh[i];                         \
            *(f16x4*)&sAl[px * 40 + icq * 4] = rl[i];                         \
        }                                                                     \
    }

    f32x4 acc[RH][2];
    #pragma unroll
    for (int r = 0; r < RH; ++r)
        #pragma unroll
        for (int nt = 0; nt < 2; ++nt) acc[r][nt] = (f32x4){0.f, 0.f, 0.f, 0.f};

    S2_PREF(0)
    S2_WRITE()
    __syncthreads();

    for (int kc = 0; kc < 4; ++kc) {
        if (kc < 3) { S2_PREF((kc + 1) * 32) }

        for (int ky = 0; ky < 3; ++ky)
        for (int kx = 0; kx < 3; ++kx) {
            const int tap = ky * 3 + kx;
            const _Float16* wth = whi + (size_t)tap * 16384;
            const _Float16* wtl = wlo + (size_t)tap * 16384;
            f16x8 bh[2], bl[2];
            #pragma unroll
            for (int nt = 0; nt < 2; ++nt) {
                int oc = ocb + wn * 32 + nt * 16 + lm;
                size_t o = (size_t)oc * 128 + kc * 32 + lq * 8;
                bh[nt] = *(const f16x8*)(wth + o);
                bl[nt] = *(const f16x8*)(wtl + o);
            }
            __builtin_amdgcn_s_setprio(1);
            #pragma unroll
            for (int r = 0; r < RH; ++r) {
                int rin = 2 * (wm * RH + r) + ky;
                int cin = 2 * lm + kx;
                int o = (rin * 33 + cin) * 40 + lq * 8;
                f16x8 ah = *(const f16x8*)(&sAh[o]);
                f16x8 al = *(const f16x8*)(&sAl[o]);
                #pragma unroll
                for (int nt = 0; nt < 2; ++nt) {
                    acc[r][nt] = __builtin_amdgcn_mfma_f32_16x16x32_f16(ah, bh[nt], acc[r][nt], 0, 0, 0);
                    acc[r][nt] = __builtin_amdgcn_mfma_f32_16x16x32_f16(ah, bl[nt], acc[r][nt], 0, 0, 0);
                    acc[r][nt] = __builtin_amdgcn_mfma_f32_16x16x32_f16(al, bh[nt], acc[r][nt], 0, 0, 0);
                }
            }
            __builtin_amdgcn_s_setprio(0);
        }
        __syncthreads();
        if (kc < 3) { S2_WRITE() __syncthreads(); }
    }
#undef S2_PREF
#undef S2_WRITE

    float bv[2];
    #pragma unroll
    for (int nt = 0; nt < 2; ++nt) bv[nt] = bias[ocb + wn * 32 + nt * 16 + lm];
    const int Hout = Hin >> 1;
    const size_t boff = (size_t)b * Hout * Wout * 128;
    #pragma unroll
    for (int r = 0; r < RH; ++r) {
        int y = y0 + wm * RH + r;
        #pragma unroll
        for (int nt = 0; nt < 2; ++nt) {
            int oc = ocb + wn * 32 + nt * 16 + lm;
            #pragma unroll
            for (int reg = 0; reg < 4; ++reg) {
                int xo = x0 + lq * 4 + reg;
                float vv = acc[r][nt][reg] + bv[nt];
                if (RELU) vv = lrelu(vv);
                size_t oo = boff + ((size_t)y * Wout + xo) * 128 + oc;
                if (SPLITOUT) {
                    _Float16 hh = (_Float16)vv;
                    outHi[oo] = hh;
                    outLo[oo] = (_Float16)(vv - (float)hh);
                } else {
                    outF[oo] = vv;
                }
            }
        }
    }
}

// ---------------- per-pixel channel-norm + 1x1 sel conv (fp32 h, wave/pixel) ----------------
__global__ __launch_bounds__(256) void normsel_kernel(
    const float* __restrict__ h, const float* __restrict__ wsel,
    const float* __restrict__ bsel, float* __restrict__ s_lin, int totalPix)
{
    int wid = (blockIdx.x * 256 + threadIdx.x) >> 6;
    if (wid >= totalPix) return;
    int lane = threadIdx.x & 63;
    const float* hb = h + (size_t)wid * 128;
    float v1 = hb[lane], v2 = hb[lane + 64];
    float ss  = v1 * v1 + v2 * v2;
    float dot = wsel[lane] * v1 + wsel[lane + 64] * v2;
    #pragma unroll
    for (int off = 32; off > 0; off >>= 1) {
        ss  += __shfl_down(ss, off);
        dot += __shfl_down(dot, off);
    }
    if (lane == 0) s_lin[wid] = dot / (sqrtf(ss) + 1e-8f) + bsel[0];
}

// ---------------- top-16 stage 1: per-256-chunk top-16 via rank counting ----------------
__global__ __launch_bounds__(256) void topk_stage1(
    const float* __restrict__ s_lin, float* __restrict__ cand_v,
    int* __restrict__ cand_i)
{
    __shared__ float sv[256];
    int b = blockIdx.y;
    int chunk = blockIdx.x;
    int tid = threadIdx.x;
    int gidx = chunk * 256 + tid;
    float v = s_lin[b * 16384 + gidx];
    sv[tid] = v;
    __syncthreads();
    int cnt = 0;
    #pragma unroll 8
    for (int j = 0; j < 256; ++j) {
        float vj = sv[j];
        cnt += (vj > v || (vj == v && j < tid)) ? 1 : 0;
    }
    if (cnt < 16) {
        int slot = (b * 64 + chunk) * 16 + cnt;
        cand_v[slot] = v;
        cand_i[slot] = gidx;
    }
}

// ---------------- top-16 stage 2: rank 1024 candidates; also emit global max ----------------
__global__ __launch_bounds__(256) void topk_stage2(
    const float* __restrict__ cand_v, const int* __restrict__ cand_i,
    int* __restrict__ idxOut, float* __restrict__ maxOut)
{
    __shared__ float sv[1024];
    __shared__ int   si[1024];
    int b = blockIdx.y;
    int tid = threadIdx.x;
    for (int j = tid; j < 1024; j += 256) {
        sv[j] = cand_v[b * 1024 + j];
        si[j] = cand_i[b * 1024 + j];
    }
    __syncthreads();
    int e = blockIdx.x * 256 + tid;
    float v  = sv[e];
    int  idx = si[e];
    int cnt = 0;
    #pragma unroll 8
    for (int j = 0; j < 1024; ++j) {
        float vj = sv[j];
        int  ij = si[j];
        cnt += (vj > v || (vj == v && ij < idx)) ? 1 : 0;
    }
    if (cnt < 16) {
        idxOut[b * 16 + cnt] = idx & 16383;   // never emit an OOB index
        if (cnt == 0) maxOut[b] = v;          // exact global max for softmax
    }
}

// ---------------- softmax (parallel): per-chunk exp-sum -> atomicAdd denom ----------------
__global__ __launch_bounds__(256) void softmax_sum_kernel(
    const float* __restrict__ s_lin, const float* __restrict__ maxv,
    float* __restrict__ denom)
{
    __shared__ float red[4];
    int b = blockIdx.y;
    int i = blockIdx.x * 256 + threadIdx.x;
    float m = maxv[b];
    float e = expf(s_lin[b * 16384 + i] - m);
    #pragma unroll
    for (int off = 32; off > 0; off >>= 1) e += __shfl_down(e, off);
    int lane = threadIdx.x & 63, wv = threadIdx.x >> 6;
    if (lane == 0) red[wv] = e;
    __syncthreads();
    if (threadIdx.x == 0) atomicAdd(denom + b, red[0] + red[1] + red[2] + red[3]);
}

// ---------------- softmax (parallel): write feat ----------------
__global__ __launch_bounds__(256) void softmax_write_kernel(
    const float* __restrict__ s_lin, const float* __restrict__ maxv,
    const float* __restrict__ denom, float* __restrict__ feat)
{
    int b = blockIdx.y;
    int i = blockIdx.x * 256 + threadIdx.x;
    float inv = 1.f / denom[b];
    feat[b * 16384 + i] = expf(s_lin[b * 16384 + i] - maxv[b]) * inv;
}

// ---------------- latents: 1x1 values-conv at 16 selected positions (fp32 h) ----------------
__global__ __launch_bounds__(128) void latents_kernel(
    const float* __restrict__ h, const float* __restrict__ wval,
    const float* __restrict__ bval, const int* __restrict__ tki,
    float* __restrict__ outL, float* __restrict__ zbuf)
{
    int bk = blockIdx.x;          // b*16 + k
    int oc = threadIdx.x;         // 0..127
    int b = bk >> 4;
    int pix = tki[bk] & 16383;
    const float* hb = h + ((size_t)b * 16384 + pix) * 128;
    const float* wr = wval + oc * 128;
    float acc = bval[oc];
    #pragma unroll 8
    for (int ic = 0; ic < 128; ++ic) acc = fmaf(wr[ic], hb[ic], acc);
    outL[bk * 128 + oc] = acc;
    zbuf[bk * 128 + oc] = acc;
}

// ---------------- up-projection z(32,128) @ wup(128,512) + bup ----------------
// R18: k-split in lane bits [4:5]; adjacent lanes vary output -> coalesced.
__global__ __launch_bounds__(256) void upproj_kernel(
    const float* __restrict__ zbuf, const float* __restrict__ wup,
    const float* __restrict__ bup, float* __restrict__ u0, int total4)
{
    int g = blockIdx.x * 256 + threadIdx.x;
    if (g >= total4) return;
    int lane = g & 63;
    int sub = lane >> 4;                 // k-split quarter
    int tl  = lane & 15;
    int out_idx = (g >> 6) * 16 + tl;
    int a = out_idx >> 9, o = out_idx & 511;
    const float* z = zbuf + a * 128 + sub * 32;
    const float* wp_ = wup + (size_t)(sub * 32) * 512 + o;
    float acc = (sub == 0) ? bup[o] : 0.f;
    #pragma unroll 8
    for (int k = 0; k < 32; ++k) acc = fmaf(z[k], wp_[k * 512], acc);
    acc += __shfl_down(acc, 32);         // s0+s2 / s1+s3
    acc += __shfl_down(acc, 16);         // (s0+s2)+(s1+s3)
    if (sub == 0) u0[out_idx] = acc;
}

// ---------------- conv1d on 2x-repeated input, k=3 pad=1, + lrelu ----------------
// R14 ic-split + R18 coalesced lane regroup.
template<int LIN>
__global__ __launch_bounds__(256) void conv1dup_kernel(
    const float* __restrict__ in, const float* __restrict__ w,
    const float* __restrict__ bias, float* __restrict__ out, int total4)
{
    constexpr int LOUT = 2 * LIN;
    constexpr int SH = (LIN == 4) ? 3 : (LIN == 8) ? 4 : 5;
    int g = blockIdx.x * 256 + threadIdx.x;
    if (g >= total4) return;
    int lane = g & 63;
    int sub = lane >> 4;                 // ic-split quarter
    int tl  = lane & 15;
    int out_idx = (g >> 6) * 16 + tl;
    int t  = out_idx & (LOUT - 1);
    int oc = (out_idx >> SH) & 127;
    int a  = out_idx >> (SH + 7);
    float acc = (sub == 0) ? bias[oc] : 0.f;
    const float* ib = in + (size_t)a * 128 * LIN + (size_t)(sub * 32) * LIN;
    const float* wr = w + (size_t)oc * 384 + sub * 96;
    int im_ = (t - 1) >> 1, i0 = t >> 1, ip = (t + 1) >> 1;
    bool bm = (t - 1) >= 0, bp = (t + 1) < LOUT;
    #pragma unroll 4
    for (int ic = 0; ic < 32; ++ic) {
        const float* ii = ib + ic * LIN;
        const float* ww = wr + ic * 3;
        if (bm) acc = fmaf(ww[0], ii[im_], acc);
        acc = fmaf(ww[1], ii[i0], acc);
        if (bp) acc = fmaf(ww[2], ii[ip], acc);
    }
    acc += __shfl_down(acc, 32);         // s0+s2 / s1+s3
    acc += __shfl_down(acc, 16);         // (s0+s2)+(s1+s3)
    if (sub == 0) out[out_idx] = lrelu(acc);
}

// ---------------- fused pointwise heads + prefix: amp (sq), fr (sigmoid+scan), mags (sq) --------
__global__ __launch_bounds__(256) void heads_kernel(
    const float* __restrict__ u,
    const float* __restrict__ wamp, const float* __restrict__ bamp,
    const float* __restrict__ wfr,  const float* __restrict__ bfr,
    const float* __restrict__ wnz,  const float* __restrict__ bnz,
    float* __restrict__ amp, float* __restrict__ fr, float* __restrict__ mags,
    float* __restrict__ pb, int total)
{
    int idx = blockIdx.x * 256 + threadIdx.x;
    if (idx >= total) return;
    int t  = idx & 31;
    int oc = (idx >> 5) % 385;
    int a  = idx / (32 * 385);
    const float* ib = u + (size_t)a * 4096 + t;
    const float* wr; float bv;
    if (oc < 128)      { wr = wamp + oc * 128;        bv = bamp[oc]; }
    else if (oc < 256) { wr = wfr + (oc - 128) * 128; bv = bfr[oc - 128]; }
    else               { wr = wnz + (oc - 256) * 128; bv = bnz[oc - 256]; }
    float acc = bv;
    #pragma unroll 8
    for (int ic = 0; ic < 128; ++ic) acc = fmaf(wr[ic], ib[ic * 32], acc);
    if (oc < 128) {
        amp[((size_t)a * 128 + oc) * 32 + t] = acc * acc;
    } else if (oc < 256) {
        float s = 1.f / (1.f + expf(-acc));
        float fv = LOWEST_FREQ + s * (1.f - LOWEST_FREQ);
        size_t o = ((size_t)a * 128 + (oc - 128)) * 32 + t;
        fr[o] = fv;
        // fused prefix: exclusive 32-lane scan in double, reduced mod 1 rev
        double d = (double)fv;
        double incl = d;
        #pragma unroll
        for (int off = 1; off < 32; off <<= 1) {
            double up = __shfl_up(incl, off, 32);
            if (t >= off) incl += up;
        }
        double t2 = 128.0 * (incl - d);
        pb[o] = (float)(t2 - floor(t2));
    } else {
        mags[((size_t)a * 129 + (oc - 256)) * 32 + t] = acc * acc;
    }
}

// ---------------- harmonic synth + scatter-add ----------------
__global__ __launch_bounds__(256) void harm_kernel(
    const float* __restrict__ fr, const float* __restrict__ amp,
    const float* __restrict__ pb, const int* __restrict__ tki,
    float* __restrict__ outp, int total)
{
    int idx = blockIdx.x * 256 + threadIdx.x;
    if (idx >= total) return;
    int a = idx >> 13;
    int i = idx & 8191;
    int j = i >> 8;
    float il1 = (float)((i & 255) + 1);
    int base = a * 4096 + j;                  // (a*128 + c)*32 + j
    float acc = 0.f;
    #pragma unroll 4
    for (int c = 0; c < 128; ++c) {
        int o = base + c * 32;                // wave-uniform -> scalar loads
        float f = fr[o];
        float am = amp[o];
        float p = pb[o];
        float rev = fmaf(il1, 0.5f * f, p);   // phase in revolutions
        acc = fmaf(fast_sin_rev(rev), am, acc);
    }
    int b = a >> 4;
    atomicAdd(outp + (size_t)b * 32768 + (tki[a] & 16383) + i, acc);
}

// ---------------- direct rfft of noise (N=256), LDS twiddle (bit-identical) ----------------
__global__ __launch_bounds__(256) void spec_kernel(
    const float* __restrict__ noise, float* __restrict__ re,
    float* __restrict__ im, int total)
{
    __shared__ float ts[256], tc[256];
    {
        int k = threadIdx.x;
        float rev = (float)k * (1.0f / 256.0f);
        ts[k] = fast_sin_rev(rev);
        tc[k] = fast_cos_rev(rev);
    }
    __syncthreads();
    int idx = blockIdx.x * 256 + threadIdx.x;
    if (idx >= total) return;
    int f  = idx % 129;
    int aw = idx / 129;
    const float* np_ = noise + (size_t)aw * 256;
    float sr = 0.f, si = 0.f;
    int k = 0;
    for (int n = 0; n < 256; ++n) {
        float v = np_[n];
        sr = fmaf(v, tc[k], sr);
        si = fmaf(v, -ts[k], si);             // exp(-i theta)
        k = (k + f) & 255;
    }
    re[idx] = sr;
    im[idx] = si;
}

// ---------------- irfft(spec * mags) + scatter-add, LDS twiddle ----------------
__global__ __launch_bounds__(256) void nz_kernel(
    const float* __restrict__ re, const float* __restrict__ im,
    const float* __restrict__ mags, const int* __restrict__ tki,
    float* __restrict__ outp, int total)
{
    __shared__ float ts[256], tc[256];
    {
        int k = threadIdx.x;
        float rev = (float)k * (1.0f / 256.0f);
        ts[k] = fast_sin_rev(rev);
        tc[k] = fast_cos_rev(rev);
    }
    __syncthreads();
    int idx = blockIdx.x * 256 + threadIdx.x;
    if (idx >= total) return;
    int t  = idx & 255;
    int w_ = (idx >> 8) & 31;
    int a  = idx >> 13;
    const float* R = re + ((size_t)a * 32 + w_) * 129;
    const float* I = im + ((size_t)a * 32 + w_) * 129;
    const float* M = mags + (size_t)a * 129 * 32 + w_;   // m[f] = M[f*32]
    float acc = R[0] * M[0];
    int k = t & 255;
    #pragma unroll 4
    for (int f = 1; f < 128; ++f) {
        acc = fmaf(2.f * M[f * 32], fmaf(R[f], tc[k], -I[f] * ts[k]), acc);
        k = (k + t) & 255;
    }
    float sg = (t & 1) ? -1.f : 1.f;
    acc = fmaf(M[128 * 32] * sg, R[128], acc);
    acc *= (1.f / 256.f);
    int b = a >> 4;
    atomicAdd(outp + (size_t)b * 32768 + (tki[a] & 16383) + (w_ << 8) + t, acc);
}

extern "C" void kernel_launch(void* const* d_in, const int* in_sizes, int n_in,
                              void* d_out, int out_size, void* d_ws, size_t ws_size,
                              hipStream_t stream) {
    (void)n_in; (void)ws_size;
    const float* x    = (const float*)d_in[0];
    const float* pos  = (const float*)d_in[1];
    const float* wi   = (const float*)d_in[2];
    const float* bi   = (const float*)d_in[3];
    const float* wp   = (const float*)d_in[4];
    const float* bp   = (const float*)d_in[5];
    const float* ws1  = (const float*)d_in[6];
    const float* bs1  = (const float*)d_in[7];
    const float* ws2  = (const float*)d_in[8];
    const float* bs2  = (const float*)d_in[9];
    const float* ws3  = (const float*)d_in[10];
    const float* bs3  = (const float*)d_in[11];
    const float* ws4  = (const float*)d_in[12];
    const float* bs4  = (const float*)d_in[13];
    const float* wsb  = (const float*)d_in[14];
    const float* bsb  = (const float*)d_in[15];
    const float* wsel = (const float*)d_in[16];
    const float* bsel = (const float*)d_in[17];
    const float* wval = (const float*)d_in[18];
    const float* bval = (const float*)d_in[19];
    const float* wup  = (const float*)d_in[20];
    const float* bup  = (const float*)d_in[21];
    const float* wu1  = (const float*)d_in[22];
    const float* bu1  = (const float*)d_in[23];
    const float* wu2  = (const float*)d_in[24];
    const float* bu2  = (const float*)d_in[25];
    const float* wu3  = (const float*)d_in[26];
    const float* bu3  = (const float*)d_in[27];
    const float* wamp = (const float*)d_in[28];
    const float* bamp = (const float*)d_in[29];
    const float* wfr  = (const float*)d_in[30];
    const float* bfr  = (const float*)d_in[31];
    const float* wnz  = (const float*)d_in[32];
    const float* bnz  = (const float*)d_in[33];
    const float* noise= (const float*)d_in[34];

    const int B = in_sizes[0] / (128 * 128);   // = 2
    float* outp = (float*)d_out;
    float* outL = outp + (size_t)B * 32768;
    float* feat = outL + (size_t)B * 16 * 128;

    // ---- workspace layout: all regions DISJOINT ----
    const size_t BIGF = (size_t)B * 16384 * 128;
    float* hbA = (float*)d_ws;
    float* hbB = hbA + BIGF;
    _Float16* Ahi = (_Float16*)hbA;  _Float16* Alo = Ahi + BIGF;
    _Float16* Bhi = (_Float16*)hbB;  _Float16* Blo = Bhi + BIGF;
    _Float16* whi = (_Float16*)(hbB + BIGF);
    _Float16* wlo = whi + 6 * 147456;
    float* s_lin = (float*)(wlo + 6 * 147456);
    float* tscr  = s_lin + (size_t)B * 16384;          // candidate buffers live here
    int*   tki   = (int*)(tscr + (size_t)B * 16384);
    float* maxv  = (float*)(tki + 64);                 // B floats (pad 16)
    float* denom = maxv + 16;                          // B floats (pad 16)
    float* zbuf  = denom + 16;
    float* u0    = zbuf + (size_t)B * 2048;
    float* u1    = u0 + (size_t)B * 65536;
    float* ampb  = u1 + (size_t)B * 65536;
    float* frb   = ampb + (size_t)B * 65536;
    float* pbb   = frb + (size_t)B * 65536;
    float* magsb = pbb + (size_t)B * 65536;
    float* spR   = magsb + (size_t)B * 16 * 129 * 32;
    float* spI   = spR + (size_t)B * 16 * 32 * 129;

    // top-k candidate buffers carved from tscr (B*16384 floats available)
    float* cand_v = tscr;                              // B*1024 floats
    int*   cand_i = (int*)(tscr + (size_t)B * 1024);   // B*1024 ints

    hipMemsetAsync(d_out, 0, (size_t)out_size * sizeof(float), stream);
    hipMemsetAsync(denom, 0, 16 * sizeof(float), stream);

    repack_kernel<<<768, 128, 0, stream>>>(wp, ws1, ws2, ws3, ws4, wsb, whi, wlo);

    // ---- encoder conv chain (channels-last, pre-split hi/lo fp16 intermediates) ----
    {
        int total = B * 128 * 16384;
        conv_in_kernel<<<(total + 255) / 256, 256, 0, stream>>>(x, wi, bi, pos, Ahi, Alo, total);
    }
    mfma_conv_s1<8, false, false, true ><<<dim3(8, 16, B * 2), 256, 0, stream>>>(Ahi, Alo, whi + 0 * 147456, wlo + 0 * 147456, bp,  nullptr, Bhi, Blo, 128, 128);
    mfma_conv_s2<2, true, true        ><<<dim3(4, 32, B * 2), 256, 0, stream>>>(Bhi, Blo, whi + 1 * 147456, wlo + 1 * 147456, bs1, nullptr, Ahi, Alo, 128, 128);
    mfma_conv_s2<2, true, true        ><<<dim3(2, 16, B * 2), 256, 0, stream>>>(Ahi, Alo, whi + 2 * 147456, wlo + 2 * 147456, bs2, nullptr, Bhi, Blo, 64, 64);
    mfma_conv_s1<4, true,  true,  true ><<<dim3(4, 16, B * 2), 256, 0, stream>>>(Bhi, Blo, whi + 3 * 147456, wlo + 3 * 147456, bs3, nullptr, Ahi, Alo, 64, 64);
    mfma_conv_s1<8, true,  true,  true ><<<dim3(8, 16, B * 2), 256, 0, stream>>>(Ahi, Alo, whi + 4 * 147456, wlo + 4 * 147456, bs4, nullptr, Bhi, Blo, 128, 128);
    mfma_conv_s1<8, false, false, false><<<dim3(8, 16, B * 2), 256, 0, stream>>>(Bhi, Blo, whi + 5 * 147456, wlo + 5 * 147456, bsb, hbA,    nullptr, nullptr, 128, 128);
    float* h = hbA;   // (B,16384,128) channels-last fp32

    // ---- selection (topk first: stage2 also emits the exact max for softmax) ----
    {
        int totalPix = B * 16384;
        normsel_kernel<<<(totalPix * 64 + 255) / 256, 256, 0, stream>>>(h, wsel, bsel, s_lin, totalPix);
    }
    topk_stage1<<<dim3(64, B), 256, 0, stream>>>(s_lin, cand_v, cand_i);
    topk_stage2<<<dim3(4, B), 256, 0, stream>>>(cand_v, cand_i, tki, maxv);
    latents_kernel<<<B * 16, 128, 0, stream>>>(h, wval, bval, tki, outL, zbuf);

    // ---- decoder (R14 ic-split + R18 coalesced lane regroup) ----
    {
        int total4 = B * 16 * 512 * 4;
        upproj_kernel<<<(total4 + 255) / 256, 256, 0, stream>>>(zbuf, wup, bup, u0, total4);
    }
    {
        int total4 = B * 16 * 128 * 8 * 4;
        conv1dup_kernel<4><<<(total4 + 255) / 256, 256, 0, stream>>>(u0, wu1, bu1, u1, total4);
    }
    {
        int total4 = B * 16 * 128 * 16 * 4;
        conv1dup_kernel<8><<<(total4 + 255) / 256, 256, 0, stream>>>(u1, wu2, bu2, u0, total4);
    }
    {
        int total4 = B * 16 * 128 * 32 * 4;
        conv1dup_kernel<16><<<(total4 + 255) / 256, 256, 0, stream>>>(u0, wu3, bu3, u1, total4);
    }
    {
        int total = B * 16 * 385 * 32;
        heads_kernel<<<(total + 255) / 256, 256, 0, stream>>>(u1, wamp, bamp, wfr, bfr, wnz, bnz,
                                                              ampb, frb, magsb, pbb, total);
    }

    // ---- parallel softmax (feat output only) ----
    softmax_sum_kernel<<<dim3(64, B), 256, 0, stream>>>(s_lin, maxv, denom);
    softmax_write_kernel<<<dim3(64, B), 256, 0, stream>>>(s_lin, maxv, denom, feat);

    // ---- synthesis ----
    {
        int total = B * 16 * 8192;
        harm_kernel<<<(total + 255) / 256, 256, 0, stream>>>(frb, ampb, pbb, tki, outp, total);
    }
    {
        int total = B * 16 * 32 * 129;
        spec_kernel<<<(total + 255) / 256, 256, 0, stream>>>(noise, spR, spI, total);
    }
    {
        int total = B * 16 * 32 * 256;
        nz_kernel<<<(total + 255) / 256, 256, 0, stream>>>(spR, spI, magsb, tki, outp, total);
    }
}

// Round 20
// 524.950 us; speedup vs baseline: 1.0217x; 1.0217x over previous
//
#include <hip/hip_runtime.h>
#include <hip/hip_bf16.h>
#include <math.h>

#define LOWEST_FREQ (30.0f / 11025.0f)

typedef _Float16 f16x8 __attribute__((ext_vector_type(8)));
typedef _Float16 f16x4 __attribute__((ext_vector_type(4)));
typedef float f32x4 __attribute__((ext_vector_type(4)));

__device__ __forceinline__ float fast_sin_rev(float rev) {
#if __has_builtin(__builtin_amdgcn_sinf)
    return __builtin_amdgcn_sinf(rev);   // v_sin_f32: sin(2*pi*rev)
#else
    return __sinf(rev * 6.28318530717958647692f);
#endif
}
__device__ __forceinline__ float fast_cos_rev(float rev) {
#if __has_builtin(__builtin_amdgcn_cosf)
    return __builtin_amdgcn_cosf(rev);
#else
    return __cosf(rev * 6.28318530717958647692f);
#endif
}
__device__ __forceinline__ float lrelu(float x) { return x >= 0.f ? x : 0.2f * x; }

// ---------------- weight repack: 6 convs, OIHW fp32 -> [tap][oc][ic] fp16 hi/lo ----------------
__global__ __launch_bounds__(128) void repack_kernel(
    const float* __restrict__ w0, const float* __restrict__ w1,
    const float* __restrict__ w2, const float* __restrict__ w3,
    const float* __restrict__ w4, const float* __restrict__ w5,
    _Float16* __restrict__ whi, _Float16* __restrict__ wlo)
{
    __shared__ float s[1152];
    int bid = blockIdx.x;               // 0..767
    int j = bid >> 7, oc = bid & 127;
    const float* src = (j == 0) ? w0 : (j == 1) ? w1 : (j == 2) ? w2 :
                       (j == 3) ? w3 : (j == 4) ? w4 : w5;
    src += (size_t)oc * 1152;
    for (int i = threadIdx.x; i < 1152; i += 128) s[i] = src[i];
    __syncthreads();
    int ic = threadIdx.x;
    size_t base = (size_t)j * 147456 + (size_t)oc * 128 + ic;
    #pragma unroll
    for (int tap = 0; tap < 9; ++tap) {
        float v = s[ic * 9 + tap];
        _Float16 h = (_Float16)v;
        size_t o = base + (size_t)tap * 16384;
        whi[o] = h;
        wlo[o] = (_Float16)(v - (float)h);
    }
}

// ---------------- conv_in: 1ch -> 112ch 3x3 + concat pos; channels-last hi/lo fp16 out ----------------
__global__ __launch_bounds__(256) void conv_in_kernel(
    const float* __restrict__ x, const float* __restrict__ wi,
    const float* __restrict__ bi, const float* __restrict__ pos,
    _Float16* __restrict__ outHi, _Float16* __restrict__ outLo, int total)
{
    int idx = blockIdx.x * 256 + threadIdx.x;
    if (idx >= total) return;
    int c   = idx & 127;
    int pix = (idx >> 7) & 16383;
    int b   = idx >> 21;
    int y = pix >> 7, xx = pix & 127;
    float v;
    if (c < 112) {
        float acc = bi[c];
        const float* xb = x + (size_t)b * 16384;
        const float* wc = wi + c * 9;
        #pragma unroll
        for (int ky = 0; ky < 3; ++ky) {
            int gy = y + ky - 1;
            if ((unsigned)gy < 128u) {
                #pragma unroll
                for (int kx = 0; kx < 3; ++kx) {
                    int gx = xx + kx - 1;
                    if ((unsigned)gx < 128u)
                        acc = fmaf(wc[ky * 3 + kx], xb[gy * 128 + gx], acc);
                }
            }
        }
        v = acc;
    } else {
        v = pos[(c - 112) * 16384 + pix];
    }
    _Float16 h = (_Float16)v;
    outHi[idx] = h;
    outLo[idx] = (_Float16)(v - (float)h);
}

// ---------------- split-fp16 MFMA stride-1 3x3 conv (fp32-parity) ----------------
// PROTECTED FINAL (R4 config). Six variants tried across the session — all
// null or regressed. 2-barrier 256-thread structure at 2 blocks/CU is this
// conv's local optimum short of a full 8-phase counted-vmcnt rewrite.
template<int TH, bool UP2, bool RELU, bool SPLITOUT>
__global__ __launch_bounds__(256, 2) void mfma_conv_s1(
    const _Float16* __restrict__ inHi, const _Float16* __restrict__ inLo,
    const _Float16* __restrict__ whi, const _Float16* __restrict__ wlo,
    const float* __restrict__ bias, float* __restrict__ outF,
    _Float16* __restrict__ outHi, _Float16* __restrict__ outLo,
    int H, int W)
{
    constexpr int IR    = TH + 2;                 // input rows staged
    constexpr int ELEMS = IR * 18 * 16;           // f16x4 groups
    constexpr int NPREF = (ELEMS + 255) / 256;
    constexpr int RH    = TH / 2;                 // output rows per wave
    __shared__ __align__(16) _Float16 sAh[IR * 18 * 72];
    __shared__ __align__(16) _Float16 sAl[IR * 18 * 72];
    const int tid  = threadIdx.x;
    const int w    = tid >> 6, lane = tid & 63;
    const int wm   = w & 1, wn = w >> 1;
    const int lm   = lane & 15, lq = lane >> 4;
    const int b    = blockIdx.z >> 1;
    const int ocb  = (blockIdx.z & 1) * 64;
    const int x0   = blockIdx.x * 16, y0 = blockIdx.y * TH;
    const int iy0  = y0 - 1, ix0 = x0 - 1;
    const int Hp   = UP2 ? (H >> 1) : H;
    const int Wp   = UP2 ? (W >> 1) : W;
    const _Float16* inbH = inHi + (size_t)b * Hp * Wp * 128;
    const _Float16* inbL = inLo + (size_t)b * Hp * Wp * 128;
    const f16x4 zf4 = {(_Float16)0.f, (_Float16)0.f, (_Float16)0.f, (_Float16)0.f};

    f16x4 rh[NPREF], rl[NPREF];

#define S1_PREF(ICS)                                                          \
    _Pragma("unroll")                                                         \
    for (int i = 0; i < NPREF; ++i) {                                         \
        int e = tid + i * 256;                                                \
        rh[i] = zf4; rl[i] = zf4;                                             \
        if (e < ELEMS) {                                                      \
            int px = e >> 4, icq = e & 15;                                    \
            int row = px / 18, col = px - row * 18;                           \
            int gy = iy0 + row, gx = ix0 + col;                               \
            if ((unsigned)gy < (unsigned)H && (unsigned)gx < (unsigned)W) {   \
                int sy = UP2 ? (gy >> 1) : gy;                                \
                int sx = UP2 ? (gx >> 1) : gx;                                \
                size_t o = ((size_t)sy * Wp + sx) * 128 + (ICS) + icq * 4;    \
                rh[i] = *(const f16x4*)(inbH + o);                            \
                rl[i] = *(const f16x4*)(inbL + o);                            \
            }                                                                 \
        }                                                                     \
    }

#define S1_WRITE()                                                            \
    _Pragma("unroll")                                                         \
    for (int i = 0; i < NPREF; ++i) {                                         \
        int e = tid + i * 256;                                                \
        if (e < ELEMS) {                                                      \
            int px = e >> 4, icq = e & 15;                                    \
            *(f16x4*)&sAh[px * 72 + icq * 4] = rh[i];                         \
            *(f16x4*)&sAl[px * 72 + icq * 4] = rl[i];                         \
        }                                                                     \
    }

    f32x4 acc[RH][2];
    #pragma unroll
    for (int r = 0; r < RH; ++r)
        #pragma unroll
        for (int nt = 0; nt < 2; ++nt) acc[r][nt] = (f32x4){0.f, 0.f, 0.f, 0.f};

    S1_PREF(0)
    S1_WRITE()
    __syncthreads();

    for (int ics2 = 0; ics2 < 2; ++ics2) {
        const int ics = ics2 * 64;
        if (ics2 == 0) { S1_PREF(64) }   // global loads in flight across MFMA phase

        for (int ky = 0; ky < 3; ++ky)
        for (int kx = 0; kx < 3; ++kx) {
            const int tap = ky * 3 + kx;
            const _Float16* wth = whi + (size_t)tap * 16384;
            const _Float16* wtl = wlo + (size_t)tap * 16384;
            #pragma unroll
            for (int kc = 0; kc < 2; ++kc) {
                f16x8 bh[2], bl[2];
                #pragma unroll
                for (int nt = 0; nt < 2; ++nt) {
                    int oc = ocb + wn * 32 + nt * 16 + lm;
                    size_t o = (size_t)oc * 128 + ics + kc * 32 + lq * 8;
                    bh[nt] = *(const f16x8*)(wth + o);
                    bl[nt] = *(const f16x8*)(wtl + o);
                }
                __builtin_amdgcn_s_setprio(1);
                #pragma unroll
                for (int r = 0; r < RH; ++r) {
                    int rin = wm * RH + r + ky;
                    int cin = lm + kx;
                    int o = (rin * 18 + cin) * 72 + kc * 32 + lq * 8;
                    f16x8 ah = *(const f16x8*)(&sAh[o]);
                    f16x8 al = *(const f16x8*)(&sAl[o]);
                    #pragma unroll
                    for (int nt = 0; nt < 2; ++nt) {
                        acc[r][nt] = __builtin_amdgcn_mfma_f32_16x16x32_f16(ah, bh[nt], acc[r][nt], 0, 0, 0);
                        acc[r][nt] = __builtin_amdgcn_mfma_f32_16x16x32_f16(ah, bl[nt], acc[r][nt], 0, 0, 0);
                        acc[r][nt] = __builtin_amdgcn_mfma_f32_16x16x32_f16(al, bh[nt], acc[r][nt], 0, 0, 0);
                    }
                }
                __builtin_amdgcn_s_setprio(0);
            }
        }
        __syncthreads();                         // all reads of current chunk done
        if (ics2 == 0) { S1_WRITE() __syncthreads(); }
    }
#undef S1_PREF
#undef S1_WRITE

    float bv[2];
    #pragma unroll
    for (int nt = 0; nt < 2; ++nt) bv[nt] = bias[ocb + wn * 32 + nt * 16 + lm];
    const size_t boff = (size_t)b * H * W * 128;
    #pragma unroll
    for (int r = 0; r < RH; ++r) {
        int y = y0 + wm * RH + r;
        #pragma unroll
        for (int nt = 0; nt < 2; ++nt) {
            int oc = ocb + wn * 32 + nt * 16 + lm;
            #pragma unroll
            for (int reg = 0; reg < 4; ++reg) {
                int xo = x0 + lq * 4 + reg;
                float vv = acc[r][nt][reg] + bv[nt];
                if (RELU) vv = lrelu(vv);
                size_t oo = boff + ((size_t)y * W + xo) * 128 + oc;
                if (SPLITOUT) {
                    _Float16 hh = (_Float16)vv;
                    outHi[oo] = hh;
                    outLo[oo] = (_Float16)(vv - (float)hh);
                } else {
                    outF[oo] = vv;
                }
            }
        }
    }
}

// ---------------- split-fp16 MFMA stride-2 3x3 conv (fp32-parity) ----------------
// R7 decomposition (PROTECTED): 64-oc blocks, waves split, TH rows/block.
// R19's TH=2 for s2#1 regressed (fixed staging cost amortizes worse) — TH=4 final.
template<int TH, bool RELU, bool SPLITOUT>
__global__ __launch_bounds__(256, 2) void mfma_conv_s2(
    const _Float16* __restrict__ inHi, const _Float16* __restrict__ inLo,
    const _Float16* __restrict__ whi, const _Float16* __restrict__ wlo,
    const float* __restrict__ bias, float* __restrict__ outF,
    _Float16* __restrict__ outHi, _Float16* __restrict__ outLo,
    int Hin, int Win)
{
    constexpr int IR    = 2 * TH + 1;            // input rows staged
    constexpr int ELEMS = IR * 33 * 8;           // f16x4 groups to stage
    constexpr int NPREF = (ELEMS + 255) / 256;
    constexpr int RH    = TH / 2;                // rows per wave
    __shared__ __align__(16) _Float16 sAh[IR * 33 * 40];
    __shared__ __align__(16) _Float16 sAl[IR * 33 * 40];
    const int tid  = threadIdx.x;
    const int w    = tid >> 6, lane = tid & 63;
    const int lm   = lane & 15, lq = lane >> 4;
    const int wm   = w & 1, wn = w >> 1;
    const int b    = blockIdx.z >> 1;
    const int ocb  = (blockIdx.z & 1) * 64;
    const int Wout = Win >> 1;
    const int x0   = blockIdx.x * 16, y0 = blockIdx.y * TH;
    const int iy0  = blockIdx.y * 2 * TH - 1, ix0 = blockIdx.x * 32 - 1;
    const _Float16* inbH = inHi + (size_t)b * Hin * Win * 128;
    const _Float16* inbL = inLo + (size_t)b * Hin * Win * 128;
    const f16x4 zf4 = {(_Float16)0.f, (_Float16)0.f, (_Float16)0.f, (_Float16)0.f};

    f16x4 rh[NPREF], rl[NPREF];

#define S2_PREF(ICS)                                                          \
    _Pragma("unroll")                                                         \
    for (int i = 0; i < NPREF; ++i) {                                         \
        int e = tid + i * 256;                                                \
        rh[i] = zf4; rl[i] = zf4;                                             \
        if (e < ELEMS) {                                                      \
            int px = e >> 3, icq = e & 7;                                     \
            int row = px / 33, col = px - row * 33;                           \
            int gy = iy0 + row, gx = ix0 + col;                               \
            if ((unsigned)gy < (unsigned)Hin && (unsigned)gx < (unsigned)Win) { \
                size_t o = ((size_t)gy * Win + gx) * 128 + (ICS) + icq * 4;   \
                rh[i] = *(const f16x4*)(inbH + o);                            \
                rl[i] = *(const f16x4*)(inbL + o);                            \
            }                                                                 \
        }                                                                     \
    }

#define S2_WRITE()                                                            \
    _Pragma("unroll")                                                         \
    for (int i = 0; i < NPREF; ++i) {                                         \
        int e = tid + i * 256;                                                \
        if (e < ELEMS) {                                                      \
            int px = e >> 3, icq = e & 7;                                     \
            *(f16x4*)&sAh[px * 40 + icq * 4] = rh[i];                         \
            *(f16x4*)&sAl[px * 40 + icq * 4] = rl[i];                         \
        }                                                                     \
    }

    f32x4 acc[RH][2];
    #pragma unroll
    for (int r = 0; r < RH; ++r)
        #pragma unroll
        for (int nt = 0; nt < 2; ++nt) acc[r][nt] = (f32x4){0.f, 0.f, 0.f, 0.f};

    S2_PREF(0)
    S2_WRITE()
    __syncthreads();

    for (int kc = 0; kc < 4; ++kc) {
        if (kc < 3) { S2_PREF((kc + 1) * 32) }

        for (int ky = 0; ky < 3; ++ky)
        for (int kx = 0; kx < 3; ++kx) {
            const int tap = ky * 3 + kx;
            const _Float16* wth = whi + (size_t)tap * 16384;
            const _Float16* wtl = wlo + (size_t)tap * 16384;
            f16x8 bh[2], bl[2];
            #pragma unroll
            for (int nt = 0; nt < 2; ++nt) {
                int oc = ocb + wn * 32 + nt * 16 + lm;
                size_t o = (size_t)oc * 128 + kc * 32 + lq * 8;
                bh[nt] = *(const f16x8*)(wth + o);
                bl[nt] = *(const f16x8*)(wtl + o);
            }
            __builtin_amdgcn_s_setprio(1);
            #pragma unroll
            for (int r = 0; r < RH; ++r) {
                int rin = 2 * (wm * RH + r) + ky;
                int cin = 2 * lm + kx;
                int o = (rin * 33 + cin) * 40 + lq * 8;
                f16x8 ah = *(const f16x8*)(&sAh[o]);
                f16x8 al = *(const f16x8*)(&sAl[o]);
                #pragma unroll
                for (int nt = 0; nt < 2; ++nt) {
                    acc[r][nt] = __builtin_amdgcn_mfma_f32_16x16x32_f16(ah, bh[nt], acc[r][nt], 0, 0, 0);
                    acc[r][nt] = __builtin_amdgcn_mfma_f32_16x16x32_f16(ah, bl[nt], acc[r][nt], 0, 0, 0);
                    acc[r][nt] = __builtin_amdgcn_mfma_f32_16x16x32_f16(al, bh[nt], acc[r][nt], 0, 0, 0);
                }
            }
            __builtin_amdgcn_s_setprio(0);
        }
        __syncthreads();
        if (kc < 3) { S2_WRITE() __syncthreads(); }
    }
#undef S2_PREF
#undef S2_WRITE

    float bv[2];
    #pragma unroll
    for (int nt = 0; nt < 2; ++nt) bv[nt] = bias[ocb + wn * 32 + nt * 16 + lm];
    const int Hout = Hin >> 1;
    const size_t boff = (size_t)b * Hout * Wout * 128;
    #pragma unroll
    for (int r = 0; r < RH; ++r) {
        int y = y0 + wm * RH + r;
        #pragma unroll
        for (int nt = 0; nt < 2; ++nt) {
            int oc = ocb + wn * 32 + nt * 16 + lm;
            #pragma unroll
            for (int reg = 0; reg < 4; ++reg) {
                int xo = x0 + lq * 4 + reg;
                float vv = acc[r][nt][reg] + bv[nt];
                if (RELU) vv = lrelu(vv);
                size_t oo = boff + ((size_t)y * Wout + xo) * 128 + oc;
                if (SPLITOUT) {
                    _Float16 hh = (_Float16)vv;
                    outHi[oo] = hh;
                    outLo[oo] = (_Float16)(vv - (float)hh);
                } else {
                    outF[oo] = vv;
                }
            }
        }
    }
}

// ---------------- per-pixel channel-norm + 1x1 sel conv (fp32 h, wave/pixel) ----------------
__global__ __launch_bounds__(256) void normsel_kernel(
    const float* __restrict__ h, const float* __restrict__ wsel,
    const float* __restrict__ bsel, float* __restrict__ s_lin, int totalPix)
{
    int wid = (blockIdx.x * 256 + threadIdx.x) >> 6;
    if (wid >= totalPix) return;
    int lane = threadIdx.x & 63;
    const float* hb = h + (size_t)wid * 128;
    float v1 = hb[lane], v2 = hb[lane + 64];
    float ss  = v1 * v1 + v2 * v2;
    float dot = wsel[lane] * v1 + wsel[lane + 64] * v2;
    #pragma unroll
    for (int off = 32; off > 0; off >>= 1) {
        ss  += __shfl_down(ss, off);
        dot += __shfl_down(dot, off);
    }
    if (lane == 0) s_lin[wid] = dot / (sqrtf(ss) + 1e-8f) + bsel[0];
}

// ---------------- top-16 stage 1: per-256-chunk top-16 via rank counting ----------------
__global__ __launch_bounds__(256) void topk_stage1(
    const float* __restrict__ s_lin, float* __restrict__ cand_v,
    int* __restrict__ cand_i)
{
    __shared__ float sv[256];
    int b = blockIdx.y;
    int chunk = blockIdx.x;
    int tid = threadIdx.x;
    int gidx = chunk * 256 + tid;
    float v = s_lin[b * 16384 + gidx];
    sv[tid] = v;
    __syncthreads();
    int cnt = 0;
    #pragma unroll 8
    for (int j = 0; j < 256; ++j) {
        float vj = sv[j];
        cnt += (vj > v || (vj == v && j < tid)) ? 1 : 0;
    }
    if (cnt < 16) {
        int slot = (b * 64 + chunk) * 16 + cnt;
        cand_v[slot] = v;
        cand_i[slot] = gidx;
    }
}

// ---------------- top-16 stage 2: rank 1024 candidates; also emit global max ----------------
__global__ __launch_bounds__(256) void topk_stage2(
    const float* __restrict__ cand_v, const int* __restrict__ cand_i,
    int* __restrict__ idxOut, float* __restrict__ maxOut)
{
    __shared__ float sv[1024];
    __shared__ int   si[1024];
    int b = blockIdx.y;
    int tid = threadIdx.x;
    for (int j = tid; j < 1024; j += 256) {
        sv[j] = cand_v[b * 1024 + j];
        si[j] = cand_i[b * 1024 + j];
    }
    __syncthreads();
    int e = blockIdx.x * 256 + tid;
    float v  = sv[e];
    int  idx = si[e];
    int cnt = 0;
    #pragma unroll 8
    for (int j = 0; j < 1024; ++j) {
        float vj = sv[j];
        int  ij = si[j];
        cnt += (vj > v || (vj == v && ij < idx)) ? 1 : 0;
    }
    if (cnt < 16) {
        idxOut[b * 16 + cnt] = idx & 16383;   // never emit an OOB index
        if (cnt == 0) maxOut[b] = v;          // exact global max for softmax
    }
}

// ---------------- softmax (parallel): per-chunk exp-sum -> atomicAdd denom ----------------
__global__ __launch_bounds__(256) void softmax_sum_kernel(
    const float* __restrict__ s_lin, const float* __restrict__ maxv,
    float* __restrict__ denom)
{
    __shared__ float red[4];
    int b = blockIdx.y;
    int i = blockIdx.x * 256 + threadIdx.x;
    float m = maxv[b];
    float e = expf(s_lin[b * 16384 + i] - m);
    #pragma unroll
    for (int off = 32; off > 0; off >>= 1) e += __shfl_down(e, off);
    int lane = threadIdx.x & 63, wv = threadIdx.x >> 6;
    if (lane == 0) red[wv] = e;
    __syncthreads();
    if (threadIdx.x == 0) atomicAdd(denom + b, red[0] + red[1] + red[2] + red[3]);
}

// ---------------- softmax (parallel): write feat ----------------
__global__ __launch_bounds__(256) void softmax_write_kernel(
    const float* __restrict__ s_lin, const float* __restrict__ maxv,
    const float* __restrict__ denom, float* __restrict__ feat)
{
    int b = blockIdx.y;
    int i = blockIdx.x * 256 + threadIdx.x;
    float inv = 1.f / denom[b];
    feat[b * 16384 + i] = expf(s_lin[b * 16384 + i] - maxv[b]) * inv;
}

// ---------------- latents: 1x1 values-conv at 16 selected positions (fp32 h) ----------------
__global__ __launch_bounds__(128) void latents_kernel(
    const float* __restrict__ h, const float* __restrict__ wval,
    const float* __restrict__ bval, const int* __restrict__ tki,
    float* __restrict__ outL, float* __restrict__ zbuf)
{
    int bk = blockIdx.x;          // b*16 + k
    int oc = threadIdx.x;         // 0..127
    int b = bk >> 4;
    int pix = tki[bk] & 16383;
    const float* hb = h + ((size_t)b * 16384 + pix) * 128;
    const float* wr = wval + oc * 128;
    float acc = bval[oc];
    #pragma unroll 8
    for (int ic = 0; ic < 128; ++ic) acc = fmaf(wr[ic], hb[ic], acc);
    outL[bk * 128 + oc] = acc;
    zbuf[bk * 128 + oc] = acc;
}

// ---------------- up-projection z(32,128) @ wup(128,512) + bup ----------------
// R18: k-split in lane bits [4:5]; adjacent lanes vary output -> coalesced.
__global__ __launch_bounds__(256) void upproj_kernel(
    const float* __restrict__ zbuf, const float* __restrict__ wup,
    const float* __restrict__ bup, float* __restrict__ u0, int total4)
{
    int g = blockIdx.x * 256 + threadIdx.x;
    if (g >= total4) return;
    int lane = g & 63;
    int sub = lane >> 4;                 // k-split quarter
    int tl  = lane & 15;
    int out_idx = (g >> 6) * 16 + tl;
    int a = out_idx >> 9, o = out_idx & 511;
    const float* z = zbuf + a * 128 + sub * 32;
    const float* wp_ = wup + (size_t)(sub * 32) * 512 + o;
    float acc = (sub == 0) ? bup[o] : 0.f;
    #pragma unroll 8
    for (int k = 0; k < 32; ++k) acc = fmaf(z[k], wp_[k * 512], acc);
    acc += __shfl_down(acc, 32);         // s0+s2 / s1+s3
    acc += __shfl_down(acc, 16);         // (s0+s2)+(s1+s3)
    if (sub == 0) u0[out_idx] = acc;
}

// ---------------- conv1d on 2x-repeated input, k=3 pad=1, + lrelu ----------------
// R14 ic-split + R18 coalesced lane regroup.
template<int LIN>
__global__ __launch_bounds__(256) void conv1dup_kernel(
    const float* __restrict__ in, const float* __restrict__ w,
    const float* __restrict__ bias, float* __restrict__ out, int total4)
{
    constexpr int LOUT = 2 * LIN;
    constexpr int SH = (LIN == 4) ? 3 : (LIN == 8) ? 4 : 5;
    int g = blockIdx.x * 256 + threadIdx.x;
    if (g >= total4) return;
    int lane = g & 63;
    int sub = lane >> 4;                 // ic-split quarter
    int tl  = lane & 15;
    int out_idx = (g >> 6) * 16 + tl;
    int t  = out_idx & (LOUT - 1);
    int oc = (out_idx >> SH) & 127;
    int a  = out_idx >> (SH + 7);
    float acc = (sub == 0) ? bias[oc] : 0.f;
    const float* ib = in + (size_t)a * 128 * LIN + (size_t)(sub * 32) * LIN;
    const float* wr = w + (size_t)oc * 384 + sub * 96;
    int im_ = (t - 1) >> 1, i0 = t >> 1, ip = (t + 1) >> 1;
    bool bm = (t - 1) >= 0, bp = (t + 1) < LOUT;
    #pragma unroll 4
    for (int ic = 0; ic < 32; ++ic) {
        const float* ii = ib + ic * LIN;
        const float* ww = wr + ic * 3;
        if (bm) acc = fmaf(ww[0], ii[im_], acc);
        acc = fmaf(ww[1], ii[i0], acc);
        if (bp) acc = fmaf(ww[2], ii[ip], acc);
    }
    acc += __shfl_down(acc, 32);         // s0+s2 / s1+s3
    acc += __shfl_down(acc, 16);         // (s0+s2)+(s1+s3)
    if (sub == 0) out[out_idx] = lrelu(acc);
}

// ---------------- fused pointwise heads + prefix: amp (sq), fr (sigmoid+scan), mags (sq) --------
__global__ __launch_bounds__(256) void heads_kernel(
    const float* __restrict__ u,
    const float* __restrict__ wamp, const float* __restrict__ bamp,
    const float* __restrict__ wfr,  const float* __restrict__ bfr,
    const float* __restrict__ wnz,  const float* __restrict__ bnz,
    float* __restrict__ amp, float* __restrict__ fr, float* __restrict__ mags,
    float* __restrict__ pb, int total)
{
    int idx = blockIdx.x * 256 + threadIdx.x;
    if (idx >= total) return;
    int t  = idx & 31;
    int oc = (idx >> 5) % 385;
    int a  = idx / (32 * 385);
    const float* ib = u + (size_t)a * 4096 + t;
    const float* wr; float bv;
    if (oc < 128)      { wr = wamp + oc * 128;        bv = bamp[oc]; }
    else if (oc < 256) { wr = wfr + (oc - 128) * 128; bv = bfr[oc - 128]; }
    else               { wr = wnz + (oc - 256) * 128; bv = bnz[oc - 256]; }
    float acc = bv;
    #pragma unroll 8
    for (int ic = 0; ic < 128; ++ic) acc = fmaf(wr[ic], ib[ic * 32], acc);
    if (oc < 128) {
        amp[((size_t)a * 128 + oc) * 32 + t] = acc * acc;
    } else if (oc < 256) {
        float s = 1.f / (1.f + expf(-acc));
        float fv = LOWEST_FREQ + s * (1.f - LOWEST_FREQ);
        size_t o = ((size_t)a * 128 + (oc - 128)) * 32 + t;
        fr[o] = fv;
        // fused prefix: exclusive 32-lane scan in double, reduced mod 1 rev
        double d = (double)fv;
        double incl = d;
        #pragma unroll
        for (int off = 1; off < 32; off <<= 1) {
            double up = __shfl_up(incl, off, 32);
            if (t >= off) incl += up;
        }
        double t2 = 128.0 * (incl - d);
        pb[o] = (float)(t2 - floor(t2));
    } else {
        mags[((size_t)a * 129 + (oc - 256)) * 32 + t] = acc * acc;
    }
}

// ---------------- harmonic synth + scatter-add ----------------
__global__ __launch_bounds__(256) void harm_kernel(
    const float* __restrict__ fr, const float* __restrict__ amp,
    const float* __restrict__ pb, const int* __restrict__ tki,
    float* __restrict__ outp, int total)
{
    int idx = blockIdx.x * 256 + threadIdx.x;
    if (idx >= total) return;
    int a = idx >> 13;
    int i = idx & 8191;
    int j = i >> 8;
    float il1 = (float)((i & 255) + 1);
    int base = a * 4096 + j;                  // (a*128 + c)*32 + j
    float acc = 0.f;
    #pragma unroll 4
    for (int c = 0; c < 128; ++c) {
        int o = base + c * 32;                // wave-uniform -> scalar loads
        float f = fr[o];
        float am = amp[o];
        float p = pb[o];
        float rev = fmaf(il1, 0.5f * f, p);   // phase in revolutions
        acc = fmaf(fast_sin_rev(rev), am, acc);
    }
    int b = a >> 4;
    atomicAdd(outp + (size_t)b * 32768 + (tki[a] & 16383) + i, acc);
}

// ---------------- direct rfft of noise (N=256), LDS twiddle (bit-identical) ----------------
__global__ __launch_bounds__(256) void spec_kernel(
    const float* __restrict__ noise, float* __restrict__ re,
    float* __restrict__ im, int total)
{
    __shared__ float ts[256], tc[256];
    {
        int k = threadIdx.x;
        float rev = (float)k * (1.0f / 256.0f);
        ts[k] = fast_sin_rev(rev);
        tc[k] = fast_cos_rev(rev);
    }
    __syncthreads();
    int idx = blockIdx.x * 256 + threadIdx.x;
    if (idx >= total) return;
    int f  = idx % 129;
    int aw = idx / 129;
    const float* np_ = noise + (size_t)aw * 256;
    float sr = 0.f, si = 0.f;
    int k = 0;
    for (int n = 0; n < 256; ++n) {
        float v = np_[n];
        sr = fmaf(v, tc[k], sr);
        si = fmaf(v, -ts[k], si);             // exp(-i theta)
        k = (k + f) & 255;
    }
    re[idx] = sr;
    im[idx] = si;
}

// ---------------- irfft(spec * mags) + scatter-add, LDS twiddle ----------------
__global__ __launch_bounds__(256) void nz_kernel(
    const float* __restrict__ re, const float* __restrict__ im,
    const float* __restrict__ mags, const int* __restrict__ tki,
    float* __restrict__ outp, int total)
{
    __shared__ float ts[256], tc[256];
    {
        int k = threadIdx.x;
        float rev = (float)k * (1.0f / 256.0f);
        ts[k] = fast_sin_rev(rev);
        tc[k] = fast_cos_rev(rev);
    }
    __syncthreads();
    int idx = blockIdx.x * 256 + threadIdx.x;
    if (idx >= total) return;
    int t  = idx & 255;
    int w_ = (idx >> 8) & 31;
    int a  = idx >> 13;
    const float* R = re + ((size_t)a * 32 + w_) * 129;
    const float* I = im + ((size_t)a * 32 + w_) * 129;
    const float* M = mags + (size_t)a * 129 * 32 + w_;   // m[f] = M[f*32]
    float acc = R[0] * M[0];
    int k = t & 255;
    #pragma unroll 4
    for (int f = 1; f < 128; ++f) {
        acc = fmaf(2.f * M[f * 32], fmaf(R[f], tc[k], -I[f] * ts[k]), acc);
        k = (k + t) & 255;
    }
    float sg = (t & 1) ? -1.f : 1.f;
    acc = fmaf(M[128 * 32] * sg, R[128], acc);
    acc *= (1.f / 256.f);
    int b = a >> 4;
    atomicAdd(outp + (size_t)b * 32768 + (tki[a] & 16383) + (w_ << 8) + t, acc);
}

extern "C" void kernel_launch(void* const* d_in, const int* in_sizes, int n_in,
                              void* d_out, int out_size, void* d_ws, size_t ws_size,
                              hipStream_t stream) {
    (void)n_in; (void)ws_size;
    const float* x    = (const float*)d_in[0];
    const float* pos  = (const float*)d_in[1];
    const float* wi   = (const float*)d_in[2];
    const float* bi   = (const float*)d_in[3];
    const float* wp   = (const float*)d_in[4];
    const float* bp   = (const float*)d_in[5];
    const float* ws1  = (const float*)d_in[6];
    const float* bs1  = (const float*)d_in[7];
    const float* ws2  = (const float*)d_in[8];
    const float* bs2  = (const float*)d_in[9];
    const float* ws3  = (const float*)d_in[10];
    const float* bs3  = (const float*)d_in[11];
    const float* ws4  = (const float*)d_in[12];
    const float* bs4  = (const float*)d_in[13];
    const float* wsb  = (const float*)d_in[14];
    const float* bsb  = (const float*)d_in[15];
    const float* wsel = (const float*)d_in[16];
    const float* bsel = (const float*)d_in[17];
    const float* wval = (const float*)d_in[18];
    const float* bval = (const float*)d_in[19];
    const float* wup  = (const float*)d_in[20];
    const float* bup  = (const float*)d_in[21];
    const float* wu1  = (const float*)d_in[22];
    const float* bu1  = (const float*)d_in[23];
    const float* wu2  = (const float*)d_in[24];
    const float* bu2  = (const float*)d_in[25];
    const float* wu3  = (const float*)d_in[26];
    const float* bu3  = (const float*)d_in[27];
    const float* wamp = (const float*)d_in[28];
    const float* bamp = (const float*)d_in[29];
    const float* wfr  = (const float*)d_in[30];
    const float* bfr  = (const float*)d_in[31];
    const float* wnz  = (const float*)d_in[32];
    const float* bnz  = (const float*)d_in[33];
    const float* noise= (const float*)d_in[34];

    const int B = in_sizes[0] / (128 * 128);   // = 2
    float* outp = (float*)d_out;
    float* outL = outp + (size_t)B * 32768;
    float* feat = outL + (size_t)B * 16 * 128;

    // ---- workspace layout: all regions DISJOINT ----
    const size_t BIGF = (size_t)B * 16384 * 128;
    float* hbA = (float*)d_ws;
    float* hbB = hbA + BIGF;
    _Float16* Ahi = (_Float16*)hbA;  _Float16* Alo = Ahi + BIGF;
    _Float16* Bhi = (_Float16*)hbB;  _Float16* Blo = Bhi + BIGF;
    _Float16* whi = (_Float16*)(hbB + BIGF);
    _Float16* wlo = whi + 6 * 147456;
    float* s_lin = (float*)(wlo + 6 * 147456);
    float* tscr  = s_lin + (size_t)B * 16384;          // candidate buffers live here
    int*   tki   = (int*)(tscr + (size_t)B * 16384);
    float* maxv  = (float*)(tki + 64);                 // B floats (pad 16)
    float* denom = maxv + 16;                          // B floats (pad 16)
    float* zbuf  = denom + 16;
    float* u0    = zbuf + (size_t)B * 2048;
    float* u1    = u0 + (size_t)B * 65536;
    float* ampb  = u1 + (size_t)B * 65536;
    float* frb   = ampb + (size_t)B * 65536;
    float* pbb   = frb + (size_t)B * 65536;
    float* magsb = pbb + (size_t)B * 65536;
    float* spR   = magsb + (size_t)B * 16 * 129 * 32;
    float* spI   = spR + (size_t)B * 16 * 32 * 129;

    // top-k candidate buffers carved from tscr (B*16384 floats available)
    float* cand_v = tscr;                              // B*1024 floats
    int*   cand_i = (int*)(tscr + (size_t)B * 1024);   // B*1024 ints

    hipMemsetAsync(d_out, 0, (size_t)out_size * sizeof(float), stream);
    hipMemsetAsync(denom, 0, 16 * sizeof(float), stream);

    repack_kernel<<<768, 128, 0, stream>>>(wp, ws1, ws2, ws3, ws4, wsb, whi, wlo);

    // ---- encoder conv chain (channels-last, pre-split hi/lo fp16 intermediates) ----
    {
        int total = B * 128 * 16384;
        conv_in_kernel<<<(total + 255) / 256, 256, 0, stream>>>(x, wi, bi, pos, Ahi, Alo, total);
    }
    mfma_conv_s1<8, false, false, true ><<<dim3(8, 16, B * 2), 256, 0, stream>>>(Ahi, Alo, whi + 0 * 147456, wlo + 0 * 147456, bp,  nullptr, Bhi, Blo, 128, 128);
    mfma_conv_s2<4, true, true        ><<<dim3(4, 16, B * 2), 256, 0, stream>>>(Bhi, Blo, whi + 1 * 147456, wlo + 1 * 147456, bs1, nullptr, Ahi, Alo, 128, 128);
    mfma_conv_s2<2, true, true        ><<<dim3(2, 16, B * 2), 256, 0, stream>>>(Ahi, Alo, whi + 2 * 147456, wlo + 2 * 147456, bs2, nullptr, Bhi, Blo, 64, 64);
    mfma_conv_s1<4, true,  true,  true ><<<dim3(4, 16, B * 2), 256, 0, stream>>>(Bhi, Blo, whi + 3 * 147456, wlo + 3 * 147456, bs3, nullptr, Ahi, Alo, 64, 64);
    mfma_conv_s1<8, true,  true,  true ><<<dim3(8, 16, B * 2), 256, 0, stream>>>(Ahi, Alo, whi + 4 * 147456, wlo + 4 * 147456, bs4, nullptr, Bhi, Blo, 128, 128);
    mfma_conv_s1<8, false, false, false><<<dim3(8, 16, B * 2), 256, 0, stream>>>(Bhi, Blo, whi + 5 * 147456, wlo + 5 * 147456, bsb, hbA,    nullptr, nullptr, 128, 128);
    float* h = hbA;   // (B,16384,128) channels-last fp32

    // ---- selection (topk first: stage2 also emits the exact max for softmax) ----
    {
        int totalPix = B * 16384;
        normsel_kernel<<<(totalPix * 64 + 255) / 256, 256, 0, stream>>>(h, wsel, bsel, s_lin, totalPix);
    }
    topk_stage1<<<dim3(64, B), 256, 0, stream>>>(s_lin, cand_v, cand_i);
    topk_stage2<<<dim3(4, B), 256, 0, stream>>>(cand_v, cand_i, tki, maxv);
    latents_kernel<<<B * 16, 128, 0, stream>>>(h, wval, bval, tki, outL, zbuf);

    // ---- decoder (R14 ic-split + R18 coalesced lane regroup) ----
    {
        int total4 = B * 16 * 512 * 4;
        upproj_kernel<<<(total4 + 255) / 256, 256, 0, stream>>>(zbuf, wup, bup, u0, total4);
    }
    {
        int total4 = B * 16 * 128 * 8 * 4;
        conv1dup_kernel<4><<<(total4 + 255) / 256, 256, 0, stream>>>(u0, wu1, bu1, u1, total4);
    }
    {
        int total4 = B * 16 * 128 * 16 * 4;
        conv1dup_kernel<8><<<(total4 + 255) / 256, 256, 0, stream>>>(u1, wu2, bu2, u0, total4);
    }
    {
        int total4 = B * 16 * 128 * 32 * 4;
        conv1dup_kernel<16><<<(total4 + 255) / 256, 256, 0, stream>>>(u0, wu3, bu3, u1, total4);
    }
    {
        int total = B * 16 * 385 * 32;
        heads_kernel<<<(total + 255) / 256, 256, 0, stream>>>(u1, wamp, bamp, wfr, bfr, wnz, bnz,
                                                              ampb, frb, magsb, pbb, total);
    }

    // ---- parallel softmax (feat output only) ----
    softmax_sum_kernel<<<dim3(64, B), 256, 0, stream>>>(s_lin, maxv, denom);
    softmax_write_kernel<<<dim3(64, B), 256, 0, stream>>>(s_lin, maxv, denom, feat);

    // ---- synthesis ----
    {
        int total = B * 16 * 8192;
        harm_kernel<<<(total + 255) / 256, 256, 0, stream>>>(frb, ampb, pbb, tki, outp, total);
    }
    {
        int total = B * 16 * 32 * 129;
        spec_kernel<<<(total + 255) / 256, 256, 0, stream>>>(noise, spR, spI, total);
    }
    {
        int total = B * 16 * 32 * 256;
        nz_kernel<<<(total + 255) / 256, 256, 0, stream>>>(spR, spI, magsb, tki, outp, total);
    }
}